// Round 4
// baseline (1250.176 us; speedup 1.0000x reference)
//
#include <hip/hip_runtime.h>
#include <math.h>

typedef __attribute__((ext_vector_type(8))) short short8;
typedef __attribute__((ext_vector_type(4))) float f32x4;
typedef __attribute__((ext_vector_type(4))) int   int4v;

#define BB  4
#define C1  128
#define C2  256
#define HH  128
#define WW  128
#define NPT 9
#define HWN (HH*WW)

// ---------- fallback (round-1, proven) workspace: FLOAT-unit offsets ----------
#define FB_WT   0
#define FB_WOFT (C1*NPT*C2)            // 294912
#define FB_OFFP (FB_WOFT + C1*9*18)    // 315648; region = 4*18*16384 floats

// ---------- fast-path workspace: BYTE offsets ----------
#define XT_OFF    0ull                        // bf16 xT[b][h][w][c]   : 16,777,216 B
#define WB2_OFF   16777216ull                 // bf16 wB2[n][o][c]     :    589,824 B
#define WOF32_OFF (WB2_OFF + 589824ull)       // f32  wof32[c][q][81]  :     82,944 B
#define BN_OFF    (WOF32_OFF + 82944ull)      // f32  bnA/bnB[256]     :      2,048 B
#define OFFP_OFF  (BN_OFF + 2048ull)          // f32  offp[pos][20]    :  5,242,880 B
#define FAST_WS_NEED (OFFP_OFF + 5242880ull)  // 22,694,912 B

__device__ __forceinline__ ushort f2bf(float f) {
  uint u = __builtin_bit_cast(uint, f);
  u += 0x7FFFu + ((u >> 16) & 1u);            // RNE
  return (ushort)(u >> 16);
}
__device__ __forceinline__ float bf2f(ushort u) {
  return __builtin_bit_cast(float, ((uint)u) << 16);
}

// ==================== FALLBACK PATH (verbatim round-1, proven pass) ====================
__global__ __launch_bounds__(256) void fb_transpose_w(
    const float* __restrict__ w_main, const float* __restrict__ w_off,
    float* __restrict__ ws) {
  int d = blockIdx.x * 256 + threadIdx.x;
  if (d < C1 * NPT * C2) {
    int o = d & 255; int cn = d >> 8; int n = cn % NPT; int c = cn / NPT;
    ws[FB_WT + d] = w_main[(o * C1 + c) * NPT + n];
  } else {
    int e = d - C1 * NPT * C2;
    if (e < C1 * 9 * 18) {
      int oc = e % 18; int t = e / 18; int tap = t % 9; int c = t / 9;
      ws[FB_WOFT + e] = w_off[(oc * C1 + c) * 9 + tap];
    }
  }
}

__global__ __launch_bounds__(256) void fb_off_conv(
    const float* __restrict__ x, const float* __restrict__ b_off,
    const float* __restrict__ ws, float* __restrict__ offp) {
  int gid = blockIdx.x * 256 + threadIdx.x;
  int w = gid & (WW - 1);
  int h = (gid >> 7) & (HH - 1);
  int b = gid >> 14;
  const float* wofT = ws + FB_WOFT;
  float acc[18];
#pragma unroll
  for (int oc = 0; oc < 18; ++oc) acc[oc] = b_off[oc];
  const float* xb = x + (size_t)b * C1 * HWN;
  for (int c = 0; c < C1; ++c) {
    const float* xc = xb + c * HWN;
    const float* wc = wofT + c * 9 * 18;
#pragma unroll
    for (int kh = 0; kh < 3; ++kh) {
      int hh = h + kh - 1;
      bool hv = (unsigned)hh < (unsigned)HH;
#pragma unroll
      for (int kw = 0; kw < 3; ++kw) {
        int wwi = w + kw - 1;
        bool v = hv && ((unsigned)wwi < (unsigned)WW);
        float xv = v ? xc[hh * WW + wwi] : 0.f;
        const float* wp = wc + (kh * 3 + kw) * 18;
#pragma unroll
        for (int oc = 0; oc < 18; ++oc) acc[oc] = fmaf(xv, wp[oc], acc[oc]);
      }
    }
  }
#pragma unroll
  for (int oc = 0; oc < 18; ++oc)
    offp[((b * 18 + oc) * HWN) + h * WW + w] = acc[oc];
}

__global__ __launch_bounds__(256) void fb_akconv_main(
    const float* __restrict__ x, const float* __restrict__ ws,
    const float* __restrict__ bn_gamma, const float* __restrict__ bn_beta,
    const float* __restrict__ bn_mean, const float* __restrict__ bn_var,
    float* __restrict__ out) {
  __shared__ float wgt[576][4];
  __shared__ int   sidx[576][4];
  __shared__ float xoff[2][NPT][64];

  int blk = blockIdx.x;
  int wt = blk & 1;
  int h  = (blk >> 1) & (HH - 1);
  int b  = blk >> 8;
  int w0 = wt * 64;
  int tid = threadIdx.x;

  const float* offp = ws + FB_OFFP;

  for (int t = tid; t < 576; t += 256) {
    int n = t >> 6; int wl = t & 63; int wp_ = w0 + wl;
    float ox = offp[((b * 18 + n) * HWN) + h * WW + wp_];
    float oy = offp[((b * 18 + 9 + n) * HWN) + h * WW + wp_];
    float px = ox + (float)(n / 3) + (float)h;
    float py = oy + (float)(n % 3) + (float)wp_;
    px = fminf(fmaxf(px, 0.f), (float)(HH - 1));
    py = fminf(fmaxf(py, 0.f), (float)(WW - 1));
    float x0 = floorf(px);
    float y0 = floorf(py);
    float x1 = fminf(x0 + 1.f, (float)(HH - 1));
    float y1 = fminf(y0 + 1.f, (float)(WW - 1));
    float glt = (1.f + (x0 - px)) * (1.f + (y0 - py));
    float grb = (1.f - (x1 - px)) * (1.f - (y1 - py));
    float glb = (1.f + (x0 - px)) * (1.f - (y1 - py));
    float grt = (1.f - (x1 - px)) * (1.f + (y0 - py));
    int ix0 = (int)x0, iy0 = (int)y0, ix1 = (int)x1, iy1 = (int)y1;
    sidx[t][0] = ix0 * WW + iy0; wgt[t][0] = glt;
    sidx[t][1] = ix1 * WW + iy1; wgt[t][1] = grb;
    sidx[t][2] = ix0 * WW + iy1; wgt[t][2] = glb;
    sidx[t][3] = ix1 * WW + iy0; wgt[t][3] = grt;
  }
  __syncthreads();

  const float* xb = x + (size_t)b * C1 * HWN;
  const float* wT = ws + FB_WT;

  float acc[64];
#pragma unroll
  for (int i = 0; i < 64; ++i) acc[i] = 0.f;

  int wl = tid & 63;
  int og = tid >> 6;
  int ogu = __builtin_amdgcn_readfirstlane(og);

  for (int c = 0; c < C1; ++c) {
    const float* xc = xb + c * HWN;
    int buf = c & 1;
    for (int t = tid; t < 576; t += 256) {
      float v = wgt[t][0] * xc[sidx[t][0]] + wgt[t][1] * xc[sidx[t][1]]
              + wgt[t][2] * xc[sidx[t][2]] + wgt[t][3] * xc[sidx[t][3]];
      xoff[buf][t >> 6][t & 63] = v;
    }
    __syncthreads();
    float s[NPT];
#pragma unroll
    for (int n = 0; n < NPT; ++n) s[n] = xoff[buf][n][wl];
    const float* wp = wT + c * (NPT * C2) + ogu * 64;
#pragma unroll
    for (int n = 0; n < NPT; ++n) {
      const float* wpn = wp + n * C2;
#pragma unroll
      for (int oi = 0; oi < 64; ++oi)
        acc[oi] = fmaf(s[n], wpn[oi], acc[oi]);
    }
  }

  float* ob = out + ((size_t)b * C2) * HWN + h * WW + w0 + wl;
#pragma unroll
  for (int oi = 0; oi < 64; ++oi) {
    int o = ogu * 64 + oi;
    float inv = bn_gamma[o] * rsqrtf(bn_var[o] + 1e-5f);
    float sh = bn_beta[o] - bn_mean[o] * inv;
    float v = acc[oi] * inv + sh;
    float r = v / (1.f + __expf(-v));
    ob[(size_t)o * HWN] = r;
  }
}

// ==================== liveness probe ====================
__global__ void probe_ws(float* ws) { ws[threadIdx.x] = 1.0f; }

// ==================== FAST PATH (gated on ws_size) ====================
__global__ __launch_bounds__(256) void prep(
    const float* __restrict__ w_main, const float* __restrict__ w_off,
    const float* __restrict__ g, const float* __restrict__ be,
    const float* __restrict__ mu, const float* __restrict__ var,
    ushort* ws_u, float* ws_f) {
  int t = blockIdx.x * 256 + threadIdx.x;
  if (t < C1 * NPT * C2) {
    int c = t & 127, o = (t >> 7) & 255, n = t >> 15;
    ws_u[WB2_OFF / 2 + t] = f2bf(w_main[(o * C1 + c) * NPT + n]);
  } else if (t < C1 * NPT * C2 + 128 * 2 * 81) {
    int e = t - C1 * NPT * C2;
    int c2 = e / 81, r81 = e - c2 * 81;
    int q = c2 & 1, c = c2 >> 1;
    int tap = r81 / 9, i = r81 - tap * 9;
    int oc = q * 9 + i;
    ws_f[WOF32_OFF / 4 + e] = w_off[(oc * C1 + c) * 9 + tap];
  } else if (t < C1 * NPT * C2 + 128 * 2 * 81 + C2) {
    int o = t - (C1 * NPT * C2 + 128 * 2 * 81);
    float inv = g[o] * rsqrtf(var[o] + 1e-5f);
    ws_f[BN_OFF / 4 + o] = inv;
    ws_f[BN_OFF / 4 + 256 + o] = be[o] - mu[o] * inv;
  }
}

__global__ __launch_bounds__(256) void transpose_x(
    const float* __restrict__ x, ushort* ws_u) {
  __shared__ __align__(16) ushort tile[32][68];
  int bid = blockIdx.x;
  int wt = bid & 1, h = (bid >> 1) & 127, cb = (bid >> 8) & 3, b = bid >> 10;
  int c0 = cb * 32, w0 = wt * 64;
  int tid = threadIdx.x;
  int wl = tid & 63, rr = tid >> 6;
#pragma unroll
  for (int it = 0; it < 8; ++it) {
    int ci = it * 4 + rr;
    tile[ci][wl] = f2bf(x[(((size_t)b * C1 + c0 + ci) * HWN) + h * WW + w0 + wl]);
  }
  __syncthreads();
  int wl2 = tid >> 2, cg = tid & 3;
  short8 pk;
#pragma unroll
  for (int k = 0; k < 8; ++k) pk[k] = (short)tile[cg * 8 + k][wl2];
  *(short8*)(ws_u + XT_OFF / 2 +
             (((size_t)(b * HH + h) * WW + w0 + wl2) * C1 + c0 + cg * 8)) = pk;
}

__global__ __launch_bounds__(256) void off_conv_f32(
    const float* __restrict__ x, const float* __restrict__ b_off,
    float* ws_f) {
  __shared__ float tile[2][3][132];
  int bid = blockIdx.x;
  int h = bid & 127, b = bid >> 7;
  int tid = threadIdx.x;
  int w = tid & 127, q = tid >> 7;
  int qu = __builtin_amdgcn_readfirstlane(q);
  const float* wq = ws_f + WOF32_OFF / 4 + qu * 81;
  const float* xb = x + (size_t)b * C1 * HWN;
  float* offp = ws_f + OFFP_OFF / 4;

  float acc[9];
#pragma unroll
  for (int i = 0; i < 9; ++i) acc[i] = b_off[qu * 9 + i];

#define STAGE_OC(dstbuf, cc)                                          \
  {                                                                   \
    int idx = tid;                                                    \
    _Pragma("unroll")                                                 \
    for (int it = 0; it < 2; ++it) {                                  \
      if (idx < 396) {                                                \
        int kh = idx / 132;                                           \
        int col = idx - kh * 132;                                     \
        int hh = h + kh - 1;                                          \
        int wwi = col - 1;                                            \
        float v = 0.f;                                                \
        if ((unsigned)hh < 128u && (unsigned)wwi < 128u)              \
          v = xb[(size_t)(cc) * HWN + hh * 128 + wwi];                \
        tile[dstbuf][kh][col] = v;                                    \
      }                                                               \
      idx += 256;                                                     \
    }                                                                 \
  }

  STAGE_OC(0, 0);
  __syncthreads();
  for (int c = 0; c < C1; ++c) {
    int buf = c & 1;
    if (c < C1 - 1) STAGE_OC(buf ^ 1, c + 1);
    float xv[9];
#pragma unroll
    for (int kh = 0; kh < 3; ++kh)
#pragma unroll
      for (int kw = 0; kw < 3; ++kw)
        xv[kh * 3 + kw] = tile[buf][kh][w + kw];
    const float* wp = wq + c * 162;
#pragma unroll
    for (int tap = 0; tap < 9; ++tap)
#pragma unroll
      for (int i = 0; i < 9; ++i)
        acc[i] = fmaf(xv[tap], wp[tap * 9 + i], acc[i]);
    __syncthreads();
  }
  int pos = (b * HH + h) * WW + w;
#pragma unroll
  for (int i = 0; i < 9; ++i) offp[pos * 20 + qu * 9 + i] = acc[i];
#undef STAGE_OC
}

__global__ __launch_bounds__(256) void akconv_main_mfma(
    const ushort* ws_u, const float* ws_f, float* out) {
  __shared__ __align__(16) int4v sidx[576];
  __shared__ __align__(16) f32x4 swgt[576];
  __shared__ __align__(16) ushort alds[2][2048];

  int tid = threadIdx.x;
  int blk = blockIdx.x;
  int wt = blk & 1, h = (blk >> 1) & 127, b = blk >> 8;
  int w0 = wt * 64;
  const float* offp = ws_f + OFFP_OFF / 4;

  for (int t = tid; t < 576; t += 256) {
    int n = t >> 6, wl = t & 63;
    int pos = (b * HH + h) * WW + w0 + wl;
    float ox = offp[pos * 20 + n];
    float oy = offp[pos * 20 + 9 + n];
    float px = ox + (float)(n / 3) + (float)h;
    float py = oy + (float)(n - (n / 3) * 3) + (float)(w0 + wl);
    px = fminf(fmaxf(px, 0.f), 127.f);
    py = fminf(fmaxf(py, 0.f), 127.f);
    float x0 = floorf(px), y0 = floorf(py);
    float x1 = fminf(x0 + 1.f, 127.f), y1 = fminf(y0 + 1.f, 127.f);
    f32x4 g;
    g[0] = (1.f + (x0 - px)) * (1.f + (y0 - py));
    g[1] = (1.f - (x1 - px)) * (1.f - (y1 - py));
    g[2] = (1.f + (x0 - px)) * (1.f - (y1 - py));
    g[3] = (1.f - (x1 - px)) * (1.f + (y0 - py));
    int ix0 = (int)x0, iy0 = (int)y0, ix1 = (int)x1, iy1 = (int)y1;
    int4v iv;
    iv[0] = (ix0 * WW + iy0) * 256;
    iv[1] = (ix1 * WW + iy1) * 256;
    iv[2] = (ix0 * WW + iy1) * 256;
    iv[3] = (ix1 * WW + iy0) * 256;
    sidx[t] = iv;
    swgt[t] = g;
  }

  const char* xTb = (const char*)ws_u + (size_t)b * (HWN * 256);
  const ushort* wB2 = ws_u + WB2_OFF / 2;
  int lane = tid & 63, r = lane & 15, kg = lane >> 4;
  int m = tid >> 2, coct = tid & 3;
  int aw_idx = m * 32 + ((coct ^ (m & 3)) * 8);

  f32x4 acc[4][4];
#pragma unroll
  for (int mi = 0; mi < 4; ++mi)
#pragma unroll
    for (int oi = 0; oi < 4; ++oi) acc[mi][oi] = (f32x4)0.0f;

  short8 bcur[4], bnext[4];
#pragma unroll
  for (int oi = 0; oi < 4; ++oi)
    bcur[oi] = *(const short8*)(wB2 + ((oi * 16 + r) * C1 + kg * 8));

  __syncthreads();

  for (int s = 0; s < 36; ++s) {
    int n = s >> 2, cb = s & 3;
    int buf = s & 1;
    {
      int e = n * 64 + m;
      int coff = cb * 64 + coct * 16;
      int4v iv = sidx[e];
      f32x4 g = swgt[e];
      short8 v0 = *(const short8*)(xTb + iv[0] + coff);
      short8 v1 = *(const short8*)(xTb + iv[1] + coff);
      short8 v2 = *(const short8*)(xTb + iv[2] + coff);
      short8 v3 = *(const short8*)(xTb + iv[3] + coff);
      short8 pk;
#pragma unroll
      for (int j = 0; j < 8; ++j) {
        float f = g[0] * bf2f((ushort)v0[j]) + g[1] * bf2f((ushort)v1[j])
                + g[2] * bf2f((ushort)v2[j]) + g[3] * bf2f((ushort)v3[j]);
        pk[j] = (short)f2bf(f);
      }
      *(short8*)(&alds[buf][aw_idx]) = pk;
    }
    if (s < 35) {
      int n2 = (s + 1) >> 2, cb2 = (s + 1) & 3;
#pragma unroll
      for (int oi = 0; oi < 4; ++oi)
        bnext[oi] = *(const short8*)(wB2 + ((n2 * C2 + oi * 16 + r) * C1 + cb2 * 32 + kg * 8));
    }
    __syncthreads();
    short8 af[4];
#pragma unroll
    for (int mi = 0; mi < 4; ++mi) {
      int row = mi * 16 + r;
      af[mi] = *(const short8*)(&alds[buf][row * 32 + ((kg ^ (r & 3)) * 8)]);
    }
#pragma unroll
    for (int mi = 0; mi < 4; ++mi)
#pragma unroll
      for (int oi = 0; oi < 4; ++oi)
        acc[mi][oi] = __builtin_amdgcn_mfma_f32_16x16x32_bf16(bcur[oi], af[mi], acc[mi][oi], 0, 0, 0);
#pragma unroll
    for (int oi = 0; oi < 4; ++oi) bcur[oi] = bnext[oi];
  }

  const float* bnA = ws_f + BN_OFF / 4;
  const float* bnB = bnA + 256;
#pragma unroll
  for (int oi = 0; oi < 4; ++oi) {
#pragma unroll
    for (int mi = 0; mi < 4; ++mi) {
#pragma unroll
      for (int j = 0; j < 4; ++j) {
        int o = oi * 16 + kg * 4 + j;
        float sA = bnA[o], sB = bnB[o];
        float v = acc[mi][oi][j] * sA + sB;
        float sv = v / (1.f + __expf(-v));
        out[(((size_t)b * C2 + o) * HWN) + h * WW + w0 + mi * 16 + r] = sv;
      }
    }
  }
}

extern "C" void kernel_launch(void* const* d_in, const int* in_sizes, int n_in,
                              void* d_out, int out_size, void* d_ws, size_t ws_size,
                              hipStream_t stream) {
  const float* x        = (const float*)d_in[0];
  const float* w_off    = (const float*)d_in[1];
  const float* b_off    = (const float*)d_in[2];
  const float* w_main   = (const float*)d_in[3];
  const float* bn_gamma = (const float*)d_in[4];
  const float* bn_beta  = (const float*)d_in[5];
  const float* bn_mean  = (const float*)d_in[6];
  const float* bn_var   = (const float*)d_in[7];
  ushort* ws_u = (ushort*)d_ws;
  float*  ws_f = (float*)d_ws;
  float*  out  = (float*)d_out;

  // --- A) proven fallback path (always runs first, produces correct out) ---
  int fb_tot = C1 * NPT * C2 + C1 * 9 * 18;
  fb_transpose_w<<<(fb_tot + 255) / 256, 256, 0, stream>>>(w_main, w_off, ws_f);
  fb_off_conv<<<(BB * HWN) / 256, 256, 0, stream>>>(x, b_off, ws_f, ws_f + FB_OFFP);
  fb_akconv_main<<<BB * HH * 2, 256, 0, stream>>>(
      x, ws_f, bn_gamma, bn_beta, bn_mean, bn_var, out);

  // --- B) liveness probe (visible in rocprof; writes dead FB_WT region) ---
  probe_ws<<<1, 64, 0, stream>>>(ws_f);

  // --- C) fast path: only if workspace is large enough; overwrites out ---
  if (ws_size >= FAST_WS_NEED) {
    int prep_tasks = C1 * NPT * C2 + 128 * 2 * 81 + C2;
    prep<<<(prep_tasks + 255) / 256, 256, 0, stream>>>(
        w_main, w_off, bn_gamma, bn_beta, bn_mean, bn_var, ws_u, ws_f);
    transpose_x<<<BB * 4 * HH * 2, 256, 0, stream>>>(x, ws_u);
    off_conv_f32<<<BB * HH, 256, 0, stream>>>(x, b_off, ws_f);
    akconv_main_mfma<<<BB * HH * 2, 256, 0, stream>>>(ws_u, ws_f, out);
  }
}

// Round 5
// 284.762 us; speedup vs baseline: 4.3903x; 4.3903x over previous
//
#include <hip/hip_runtime.h>
#include <math.h>

typedef __attribute__((ext_vector_type(8))) short short8;
typedef __attribute__((ext_vector_type(4))) float f32x4;
typedef __attribute__((ext_vector_type(4))) int   int4v;

#define BB  4
#define C1  128
#define C2  256
#define HH  128
#define WW  128
#define NPT 9
#define HWN (HH*WW)

// ---- workspace byte offsets (all 256-aligned) ----
#define XT_OFF    0ull                        // bf16 xT[b][h][w][c]   : 16,777,216 B
#define WB2_OFF   16777216ull                 // bf16 wB2[n][o][c]     :    589,824 B
#define WOF32_OFF (WB2_OFF + 589824ull)       // f32  wof32[c][q][81]  :     82,944 B
#define BN_OFF    (WOF32_OFF + 82944ull)      // f32  bnA/bnB[256]     :      2,048 B
#define OFFP_OFF  (BN_OFF + 2048ull)          // f32  offp[pos][20]    :  5,242,880 B

__device__ __forceinline__ ushort f2bf(float f) {
  uint u = __builtin_bit_cast(uint, f);
  u += 0x7FFFu + ((u >> 16) & 1u);            // RNE
  return (ushort)(u >> 16);
}
__device__ __forceinline__ float bf2f(ushort u) {
  return __builtin_bit_cast(float, ((uint)u) << 16);
}

// ---------------- weight / BN prep ----------------
__global__ __launch_bounds__(256) void prep(
    const float* __restrict__ w_main, const float* __restrict__ w_off,
    const float* __restrict__ g, const float* __restrict__ be,
    const float* __restrict__ mu, const float* __restrict__ var,
    ushort* ws_u, float* ws_f) {
  int t = blockIdx.x * 256 + threadIdx.x;
  if (t < C1 * NPT * C2) {                        // wB2[n][o][c] = w_main[o][c][n]
    int c = t & 127, o = (t >> 7) & 255, n = t >> 15;
    ws_u[WB2_OFF / 2 + t] = f2bf(w_main[(o * C1 + c) * NPT + n]);
  } else if (t < C1 * NPT * C2 + 128 * 2 * 81) {  // wof32[(c*2+q)*81 + tap*9 + i]
    int e = t - C1 * NPT * C2;
    int c2 = e / 81, r81 = e - c2 * 81;
    int q = c2 & 1, c = c2 >> 1;
    int tap = r81 / 9, i = r81 - tap * 9;
    int oc = q * 9 + i;
    ws_f[WOF32_OFF / 4 + e] = w_off[(oc * C1 + c) * 9 + tap];
  } else if (t < C1 * NPT * C2 + 128 * 2 * 81 + C2) {
    int o = t - (C1 * NPT * C2 + 128 * 2 * 81);
    float inv = g[o] * rsqrtf(var[o] + 1e-5f);
    ws_f[BN_OFF / 4 + o] = inv;
    ws_f[BN_OFF / 4 + 256 + o] = be[o] - mu[o] * inv;
  }
}

// ---------------- x -> xT[b][h][w][c] bf16 (c-contiguous) ----------------
__global__ __launch_bounds__(256) void transpose_x(
    const float* __restrict__ x, ushort* ws_u) {
  __shared__ __align__(16) ushort tile[32][68];
  int bid = blockIdx.x;
  int wt = bid & 1, h = (bid >> 1) & 127, cb = (bid >> 8) & 3, b = bid >> 10;
  int c0 = cb * 32, w0 = wt * 64;
  int tid = threadIdx.x;
  int wl = tid & 63, rr = tid >> 6;
#pragma unroll
  for (int it = 0; it < 8; ++it) {
    int ci = it * 4 + rr;
    tile[ci][wl] = f2bf(x[(((size_t)b * C1 + c0 + ci) * HWN) + h * WW + w0 + wl]);
  }
  __syncthreads();
  int wl2 = tid >> 2, cg = tid & 3;
  short8 pk;
#pragma unroll
  for (int k = 0; k < 8; ++k) pk[k] = (short)tile[cg * 8 + k][wl2];
  *(short8*)(ws_u + XT_OFF / 2 +
             (((size_t)(b * HH + h) * WW + w0 + wl2) * C1 + c0 + cg * 8)) = pk;
}

// ---------------- fp32 offset conv (3x3, pad 1), LDS-staged ----------------
__global__ __launch_bounds__(256) void off_conv_f32(
    const float* __restrict__ x, const float* __restrict__ b_off,
    float* ws_f) {
  __shared__ float tile[2][3][132];
  int bid = blockIdx.x;                 // b*128 + h
  int h = bid & 127, b = bid >> 7;
  int tid = threadIdx.x;
  int w = tid & 127, q = tid >> 7;
  int qu = __builtin_amdgcn_readfirstlane(q);
  const float* wq = ws_f + WOF32_OFF / 4 + qu * 81;
  const float* xb = x + (size_t)b * C1 * HWN;
  float* offp = ws_f + OFFP_OFF / 4;

  float acc[9];
#pragma unroll
  for (int i = 0; i < 9; ++i) acc[i] = b_off[qu * 9 + i];

#define STAGE_OC(dstbuf, cc)                                          \
  {                                                                   \
    int idx = tid;                                                    \
    _Pragma("unroll")                                                 \
    for (int it = 0; it < 2; ++it) {                                  \
      if (idx < 396) {                                                \
        int kh = idx / 132;                                           \
        int col = idx - kh * 132;                                     \
        int hh = h + kh - 1;                                          \
        int wwi = col - 1;                                            \
        float v = 0.f;                                                \
        if ((unsigned)hh < 128u && (unsigned)wwi < 128u)              \
          v = xb[(size_t)(cc) * HWN + hh * 128 + wwi];                \
        tile[dstbuf][kh][col] = v;                                    \
      }                                                               \
      idx += 256;                                                     \
    }                                                                 \
  }

  STAGE_OC(0, 0);
  __syncthreads();
  for (int c = 0; c < C1; ++c) {
    int buf = c & 1;
    if (c < C1 - 1) STAGE_OC(buf ^ 1, c + 1);
    float xv[9];
#pragma unroll
    for (int kh = 0; kh < 3; ++kh)
#pragma unroll
      for (int kw = 0; kw < 3; ++kw)
        xv[kh * 3 + kw] = tile[buf][kh][w + kw];
    const float* wp = wq + c * 162;
#pragma unroll
    for (int tap = 0; tap < 9; ++tap)
#pragma unroll
      for (int i = 0; i < 9; ++i)
        acc[i] = fmaf(xv[tap], wp[tap * 9 + i], acc[i]);
    __syncthreads();
  }
  int pos = (b * HH + h) * WW + w;
#pragma unroll
  for (int i = 0; i < 9; ++i) offp[pos * 20 + qu * 9 + i] = acc[i];
#undef STAGE_OC
}

// ---------------- fused gather + MFMA GEMM + BN + SiLU ----------------
__global__ __launch_bounds__(256) void akconv_main_mfma(
    const ushort* ws_u, const float* ws_f, float* out) {
  __shared__ __align__(16) int4v sidx[576];
  __shared__ __align__(16) f32x4 swgt[576];
  __shared__ __align__(16) ushort alds[2][2048];   // [buf][64 rows][32 c] swizzled

  int tid = threadIdx.x;
  int blk = blockIdx.x;
  int wt = blk & 1, h = (blk >> 1) & 127, b = blk >> 8;
  int w0 = wt * 64;
  const float* offp = ws_f + OFFP_OFF / 4;

  // phase A: bilinear indices (byte offsets into xT b-plane) + weights
  for (int t = tid; t < 576; t += 256) {
    int n = t >> 6, wl = t & 63;
    int pos = (b * HH + h) * WW + w0 + wl;
    float ox = offp[pos * 20 + n];
    float oy = offp[pos * 20 + 9 + n];
    float px = ox + (float)(n / 3) + (float)h;
    float py = oy + (float)(n - (n / 3) * 3) + (float)(w0 + wl);
    px = fminf(fmaxf(px, 0.f), 127.f);
    py = fminf(fmaxf(py, 0.f), 127.f);
    float x0 = floorf(px), y0 = floorf(py);
    float x1 = fminf(x0 + 1.f, 127.f), y1 = fminf(y0 + 1.f, 127.f);
    f32x4 g;
    g[0] = (1.f + (x0 - px)) * (1.f + (y0 - py));
    g[1] = (1.f - (x1 - px)) * (1.f - (y1 - py));
    g[2] = (1.f + (x0 - px)) * (1.f - (y1 - py));
    g[3] = (1.f - (x1 - px)) * (1.f + (y0 - py));
    int ix0 = (int)x0, iy0 = (int)y0, ix1 = (int)x1, iy1 = (int)y1;
    int4v iv;
    iv[0] = (ix0 * WW + iy0) * 256;
    iv[1] = (ix1 * WW + iy1) * 256;
    iv[2] = (ix0 * WW + iy1) * 256;
    iv[3] = (ix1 * WW + iy0) * 256;
    sidx[t] = iv;
    swgt[t] = g;
  }

  const char* xTb = (const char*)ws_u + (size_t)b * (HWN * 256);
  const ushort* wB2 = ws_u + WB2_OFF / 2;
  int lane = tid & 63, r = lane & 15, kg = lane >> 4;
  int owu = __builtin_amdgcn_readfirstlane(tid >> 6) * 64;   // wave's 64-channel slice
  int m = tid >> 2, coct = tid & 3;
  int aw_idx = m * 32 + ((coct ^ (m & 3)) * 8);   // swizzled ushort index

  f32x4 acc[4][4];
#pragma unroll
  for (int mi = 0; mi < 4; ++mi)
#pragma unroll
    for (int oi = 0; oi < 4; ++oi) acc[mi][oi] = (f32x4)0.0f;

  short8 bcur[4], bnext[4];
#pragma unroll
  for (int oi = 0; oi < 4; ++oi)
    bcur[oi] = *(const short8*)(wB2 + ((owu + oi * 16 + r) * C1 + kg * 8));

  __syncthreads();   // sidx/swgt visible

  for (int s = 0; s < 36; ++s) {
    int n = s >> 2, cb = s & 3;
    int buf = s & 1;
    // build A-tile: 64 pos x 32 c, one bf16 octet per thread
    {
      int e = n * 64 + m;
      int coff = cb * 64 + coct * 16;   // byte offset within c-row
      int4v iv = sidx[e];
      f32x4 g = swgt[e];
      short8 v0 = *(const short8*)(xTb + iv[0] + coff);
      short8 v1 = *(const short8*)(xTb + iv[1] + coff);
      short8 v2 = *(const short8*)(xTb + iv[2] + coff);
      short8 v3 = *(const short8*)(xTb + iv[3] + coff);
      short8 pk;
#pragma unroll
      for (int j = 0; j < 8; ++j) {
        float f = g[0] * bf2f((ushort)v0[j]) + g[1] * bf2f((ushort)v1[j])
                + g[2] * bf2f((ushort)v2[j]) + g[3] * bf2f((ushort)v3[j]);
        pk[j] = (short)f2bf(f);
      }
      *(short8*)(&alds[buf][aw_idx]) = pk;
    }
    // prefetch next B fragments (global, L1/L2-hot)
    if (s < 35) {
      int n2 = (s + 1) >> 2, cb2 = (s + 1) & 3;
#pragma unroll
      for (int oi = 0; oi < 4; ++oi)
        bnext[oi] = *(const short8*)(wB2 + ((n2 * C2 + owu + oi * 16 + r) * C1 + cb2 * 32 + kg * 8));
    }
    __syncthreads();
    short8 af[4];
#pragma unroll
    for (int mi = 0; mi < 4; ++mi) {
      int row = mi * 16 + r;
      af[mi] = *(const short8*)(&alds[buf][row * 32 + ((kg ^ (r & 3)) * 8)]);
    }
    // swapped operands: W-frag as A, x-frag as B -> D[row=o_sub][col=pos]
#pragma unroll
    for (int mi = 0; mi < 4; ++mi)
#pragma unroll
      for (int oi = 0; oi < 4; ++oi)
        acc[mi][oi] = __builtin_amdgcn_mfma_f32_16x16x32_bf16(bcur[oi], af[mi], acc[mi][oi], 0, 0, 0);
#pragma unroll
    for (int oi = 0; oi < 4; ++oi) bcur[oi] = bnext[oi];
  }

  // epilogue: BN + SiLU, coalesced along w (col = position)
  const float* bnA = ws_f + BN_OFF / 4;
  const float* bnB = bnA + 256;
#pragma unroll
  for (int oi = 0; oi < 4; ++oi) {
#pragma unroll
    for (int mi = 0; mi < 4; ++mi) {
#pragma unroll
      for (int j = 0; j < 4; ++j) {
        int o = owu + oi * 16 + kg * 4 + j;
        float sA = bnA[o], sB = bnB[o];
        float v = acc[mi][oi][j] * sA + sB;
        float sv = v / (1.f + __expf(-v));
        out[(((size_t)b * C2 + o) * HWN) + h * WW + w0 + mi * 16 + r] = sv;
      }
    }
  }
}

extern "C" void kernel_launch(void* const* d_in, const int* in_sizes, int n_in,
                              void* d_out, int out_size, void* d_ws, size_t ws_size,
                              hipStream_t stream) {
  const float* x        = (const float*)d_in[0];
  const float* w_off    = (const float*)d_in[1];
  const float* b_off    = (const float*)d_in[2];
  const float* w_main   = (const float*)d_in[3];
  const float* bn_gamma = (const float*)d_in[4];
  const float* bn_beta  = (const float*)d_in[5];
  const float* bn_mean  = (const float*)d_in[6];
  const float* bn_var   = (const float*)d_in[7];
  ushort* ws_u = (ushort*)d_ws;
  float*  ws_f = (float*)d_ws;
  float*  out  = (float*)d_out;

  int prep_tasks = C1 * NPT * C2 + 128 * 2 * 81 + C2;   // 315904
  prep<<<(prep_tasks + 255) / 256, 256, 0, stream>>>(
      w_main, w_off, bn_gamma, bn_beta, bn_mean, bn_var, ws_u, ws_f);
  transpose_x<<<BB * 4 * HH * 2, 256, 0, stream>>>(x, ws_u);
  off_conv_f32<<<BB * HH, 256, 0, stream>>>(x, b_off, ws_f);
  akconv_main_mfma<<<BB * HH * 2, 256, 0, stream>>>(ws_u, ws_f, out);
}

// Round 6
// 252.047 us; speedup vs baseline: 4.9601x; 1.1298x over previous
//
#include <hip/hip_runtime.h>
#include <math.h>

typedef __attribute__((ext_vector_type(8))) short short8;
typedef __attribute__((ext_vector_type(4))) float f32x4;
typedef __attribute__((ext_vector_type(4))) int   int4v;

#define BB  4
#define C1  128
#define C2  256
#define HH  128
#define WW  128
#define NPT 9
#define HWN (HH*WW)

// ---- workspace byte offsets (all 256-aligned) ----
#define XT_OFF    0ull                        // bf16 xT[b][h][w][c]   : 16,777,216 B
#define WB2_OFF   16777216ull                 // bf16 wB2[n][o][c]     :    589,824 B
#define WOF32_OFF (WB2_OFF + 589824ull)       // f32  wof32[c][q][81]  :     82,944 B
#define BN_OFF    (WOF32_OFF + 82944ull)      // f32  bnA/bnB[256]     :      2,048 B
#define OFFP_OFF  (BN_OFF + 2048ull)          // f32  offp[pos][20]    :  5,242,880 B

__device__ __forceinline__ ushort f2bf(float f) {
  uint u = __builtin_bit_cast(uint, f);
  u += 0x7FFFu + ((u >> 16) & 1u);            // RNE
  return (ushort)(u >> 16);
}
__device__ __forceinline__ float bf2f(ushort u) {
  return __builtin_bit_cast(float, ((uint)u) << 16);
}

// ---------------- weight / BN prep ----------------
__global__ __launch_bounds__(256) void prep(
    const float* __restrict__ w_main, const float* __restrict__ w_off,
    const float* __restrict__ g, const float* __restrict__ be,
    const float* __restrict__ mu, const float* __restrict__ var,
    ushort* ws_u, float* ws_f) {
  int t = blockIdx.x * 256 + threadIdx.x;
  if (t < C1 * NPT * C2) {                        // wB2[n][o][c] = w_main[o][c][n]
    int c = t & 127, o = (t >> 7) & 255, n = t >> 15;
    ws_u[WB2_OFF / 2 + t] = f2bf(w_main[(o * C1 + c) * NPT + n]);
  } else if (t < C1 * NPT * C2 + 128 * 2 * 81) {  // wof32[(c*2+q)*81 + tap*9 + i]
    int e = t - C1 * NPT * C2;
    int c2 = e / 81, r81 = e - c2 * 81;
    int q = c2 & 1, c = c2 >> 1;
    int tap = r81 / 9, i = r81 - tap * 9;
    int oc = q * 9 + i;
    ws_f[WOF32_OFF / 4 + e] = w_off[(oc * C1 + c) * 9 + tap];
  } else if (t < C1 * NPT * C2 + 128 * 2 * 81 + C2) {
    int o = t - (C1 * NPT * C2 + 128 * 2 * 81);
    float inv = g[o] * rsqrtf(var[o] + 1e-5f);
    ws_f[BN_OFF / 4 + o] = inv;
    ws_f[BN_OFF / 4 + 256 + o] = be[o] - mu[o] * inv;
  }
}

// ---------------- x -> xT[b][h][w][c] bf16 (c-contiguous) ----------------
__global__ __launch_bounds__(256) void transpose_x(
    const float* __restrict__ x, ushort* ws_u) {
  __shared__ __align__(16) ushort tile[32][68];
  int bid = blockIdx.x;
  int wt = bid & 1, h = (bid >> 1) & 127, cb = (bid >> 8) & 3, b = bid >> 10;
  int c0 = cb * 32, w0 = wt * 64;
  int tid = threadIdx.x;
  int wl = tid & 63, rr = tid >> 6;
#pragma unroll
  for (int it = 0; it < 8; ++it) {
    int ci = it * 4 + rr;
    tile[ci][wl] = f2bf(x[(((size_t)b * C1 + c0 + ci) * HWN) + h * WW + w0 + wl]);
  }
  __syncthreads();
  int wl2 = tid >> 2, cg = tid & 3;
  short8 pk;
#pragma unroll
  for (int k = 0; k < 8; ++k) pk[k] = (short)tile[cg * 8 + k][wl2];
  *(short8*)(ws_u + XT_OFF / 2 +
             (((size_t)(b * HH + h) * WW + w0 + wl2) * C1 + c0 + cg * 8)) = pk;
}

// ---------------- fp32 offset conv (3x3, pad 1), LDS-staged ----------------
__global__ __launch_bounds__(256) void off_conv_f32(
    const float* __restrict__ x, const float* __restrict__ b_off,
    float* ws_f) {
  __shared__ float tile[2][3][132];
  int bid = blockIdx.x;                 // b*128 + h
  int h = bid & 127, b = bid >> 7;
  int tid = threadIdx.x;
  int w = tid & 127, q = tid >> 7;
  int qu = __builtin_amdgcn_readfirstlane(q);
  const float* wq = ws_f + WOF32_OFF / 4 + qu * 81;
  const float* xb = x + (size_t)b * C1 * HWN;
  float* offp = ws_f + OFFP_OFF / 4;

  float acc[9];
#pragma unroll
  for (int i = 0; i < 9; ++i) acc[i] = b_off[qu * 9 + i];

#define STAGE_OC(dstbuf, cc)                                          \
  {                                                                   \
    int idx = tid;                                                    \
    _Pragma("unroll")                                                 \
    for (int it = 0; it < 2; ++it) {                                  \
      if (idx < 396) {                                                \
        int kh = idx / 132;                                           \
        int col = idx - kh * 132;                                     \
        int hh = h + kh - 1;                                          \
        int wwi = col - 1;                                            \
        float v = 0.f;                                                \
        if ((unsigned)hh < 128u && (unsigned)wwi < 128u)              \
          v = xb[(size_t)(cc) * HWN + hh * 128 + wwi];                \
        tile[dstbuf][kh][col] = v;                                    \
      }                                                               \
      idx += 256;                                                     \
    }                                                                 \
  }

  STAGE_OC(0, 0);
  __syncthreads();
  for (int c = 0; c < C1; ++c) {
    int buf = c & 1;
    if (c < C1 - 1) STAGE_OC(buf ^ 1, c + 1);
    float xv[9];
#pragma unroll
    for (int kh = 0; kh < 3; ++kh)
#pragma unroll
      for (int kw = 0; kw < 3; ++kw)
        xv[kh * 3 + kw] = tile[buf][kh][w + kw];
    const float* wp = wq + c * 162;
#pragma unroll
    for (int tap = 0; tap < 9; ++tap)
#pragma unroll
      for (int i = 0; i < 9; ++i)
        acc[i] = fmaf(xv[tap], wp[tap * 9 + i], acc[i]);
    __syncthreads();
  }
  int pos = (b * HH + h) * WW + w;
#pragma unroll
  for (int i = 0; i < 9; ++i) offp[pos * 20 + qu * 9 + i] = acc[i];
#undef STAGE_OC
}

// ---------------- fused gather + MFMA GEMM + BN + SiLU (8-wave) ----------------
__global__ __launch_bounds__(512) void akconv_main_mfma8(
    const ushort* ws_u, const float* ws_f, float* out) {
  __shared__ __align__(16) int4v sidx[576];
  __shared__ __align__(16) f32x4 swgt[576];
  __shared__ __align__(16) ushort alds[2][8192];   // [buf][64 pos][128 c], oct^=(pos&7)

  int tid = threadIdx.x;
  int blk = blockIdx.x;
  // XCD-aware decode: each XCD (blk&7) owns one b-plane and one 64-row h-band
  int xcd = blk & 7, idx = blk >> 3;        // idx in 0..127
  int b  = xcd >> 1;
  int h  = ((xcd & 1) << 6) + (idx >> 1);
  int wt = idx & 1;
  int w0 = wt * 64;
  const float* offp = ws_f + OFFP_OFF / 4;

  // phase A: bilinear indices (byte offsets into xT b-plane) + weights
  for (int t = tid; t < 576; t += 512) {
    int n = t >> 6, wl = t & 63;
    int pos = (b * HH + h) * WW + w0 + wl;
    float ox = offp[pos * 20 + n];
    float oy = offp[pos * 20 + 9 + n];
    float px = ox + (float)(n / 3) + (float)h;
    float py = oy + (float)(n - (n / 3) * 3) + (float)(w0 + wl);
    px = fminf(fmaxf(px, 0.f), 127.f);
    py = fminf(fmaxf(py, 0.f), 127.f);
    float x0 = floorf(px), y0 = floorf(py);
    float x1 = fminf(x0 + 1.f, 127.f), y1 = fminf(y0 + 1.f, 127.f);
    f32x4 g;
    g[0] = (1.f + (x0 - px)) * (1.f + (y0 - py));
    g[1] = (1.f - (x1 - px)) * (1.f - (y1 - py));
    g[2] = (1.f + (x0 - px)) * (1.f - (y1 - py));
    g[3] = (1.f - (x1 - px)) * (1.f + (y0 - py));
    int ix0 = (int)x0, iy0 = (int)y0, ix1 = (int)x1, iy1 = (int)y1;
    int4v iv;
    iv[0] = (ix0 * WW + iy0) * 256;
    iv[1] = (ix1 * WW + iy1) * 256;
    iv[2] = (ix0 * WW + iy1) * 256;
    iv[3] = (ix1 * WW + iy0) * 256;
    sidx[t] = iv;
    swgt[t] = g;
  }

  const char* xTb = (const char*)ws_u + (size_t)b * (HWN * 256);
  const ushort* wB2 = ws_u + WB2_OFF / 2;
  int lane = tid & 63, r = lane & 15, kg = lane >> 4;
  int owu = __builtin_amdgcn_readfirstlane(tid >> 6) * 32;  // wave's 32-channel slice

  // per-thread build slots: two of (pos, 16B c-octet)
  int p0  = tid >> 4;                 // 0..31
  int p1  = p0 + 32;                  // 32..63
  int oct = tid & 15;
  int coff = oct * 16;                // byte offset within 256B c-row
  int wr0 = p0 * 128 + ((oct ^ (p0 & 7)) * 8);   // swizzled ushort index
  int wr1 = p1 * 128 + ((oct ^ (p1 & 7)) * 8);

  f32x4 acc[4][2];
#pragma unroll
  for (int mi = 0; mi < 4; ++mi)
#pragma unroll
    for (int oi = 0; oi < 2; ++oi) acc[mi][oi] = (f32x4)0.0f;

  __syncthreads();   // sidx/swgt visible

  short8 gv[2][4];
  f32x4 gw0, gw1;

#define GLOAD(nn)                                                       \
  {                                                                     \
    int4v iv0 = sidx[(nn) * 64 + p0];                                   \
    int4v iv1 = sidx[(nn) * 64 + p1];                                   \
    gw0 = swgt[(nn) * 64 + p0];                                         \
    gw1 = swgt[(nn) * 64 + p1];                                         \
    _Pragma("unroll")                                                   \
    for (int k = 0; k < 4; ++k) {                                       \
      gv[0][k] = *(const short8*)(xTb + iv0[k] + coff);                 \
      gv[1][k] = *(const short8*)(xTb + iv1[k] + coff);                 \
    }                                                                   \
  }

#define GCOMBINE(bufb)                                                  \
  {                                                                     \
    short8 pk0, pk1;                                                    \
    _Pragma("unroll")                                                   \
    for (int j = 0; j < 8; ++j) {                                       \
      float f0 = gw0[0] * bf2f((ushort)gv[0][0][j])                     \
               + gw0[1] * bf2f((ushort)gv[0][1][j])                     \
               + gw0[2] * bf2f((ushort)gv[0][2][j])                     \
               + gw0[3] * bf2f((ushort)gv[0][3][j]);                    \
      float f1 = gw1[0] * bf2f((ushort)gv[1][0][j])                     \
               + gw1[1] * bf2f((ushort)gv[1][1][j])                     \
               + gw1[2] * bf2f((ushort)gv[1][2][j])                     \
               + gw1[3] * bf2f((ushort)gv[1][3][j]);                    \
      pk0[j] = (short)f2bf(f0);                                         \
      pk1[j] = (short)f2bf(f1);                                         \
    }                                                                   \
    *(short8*)(&alds[bufb][wr0]) = pk0;                                 \
    *(short8*)(&alds[bufb][wr1]) = pk1;                                 \
  }

  // prologue: build n=0 into buf 0
  GLOAD(0);
  GCOMBINE(0);
  __syncthreads();

  for (int n = 0; n < 9; ++n) {
    int buf = n & 1;
    // 1) issue next-n gathers (latency hides under MFMA phase)
    if (n < 8) GLOAD(n + 1);
    // 2) MFMA over the current 128-channel slab
#pragma unroll
    for (int kc = 0; kc < 4; ++kc) {
      short8 b0 = *(const short8*)(wB2 + ((size_t)(n * C2 + owu + r) * C1 + kc * 32 + kg * 8));
      short8 b1 = *(const short8*)(wB2 + ((size_t)(n * C2 + owu + 16 + r) * C1 + kc * 32 + kg * 8));
#pragma unroll
      for (int mi = 0; mi < 4; ++mi) {
        short8 a = *(const short8*)(&alds[buf][(mi * 16 + r) * 128 + (((kc * 4 + kg) ^ (r & 7)) * 8)]);
        acc[mi][0] = __builtin_amdgcn_mfma_f32_16x16x32_bf16(b0, a, acc[mi][0], 0, 0, 0);
        acc[mi][1] = __builtin_amdgcn_mfma_f32_16x16x32_bf16(b1, a, acc[mi][1], 0, 0, 0);
      }
    }
    // 3) combine + write next slab
    if (n < 8) GCOMBINE(buf ^ 1);
    __syncthreads();
  }
#undef GLOAD
#undef GCOMBINE

  // epilogue: BN + SiLU, coalesced along w (col = position)
  const float* bnA = ws_f + BN_OFF / 4;
  const float* bnB = bnA + 256;
#pragma unroll
  for (int oi = 0; oi < 2; ++oi) {
#pragma unroll
    for (int mi = 0; mi < 4; ++mi) {
#pragma unroll
      for (int j = 0; j < 4; ++j) {
        int o = owu + oi * 16 + kg * 4 + j;
        float sA = bnA[o], sB = bnB[o];
        float v = acc[mi][oi][j] * sA + sB;
        float sv = v / (1.f + __expf(-v));
        out[(((size_t)b * C2 + o) * HWN) + h * WW + w0 + mi * 16 + r] = sv;
      }
    }
  }
}

extern "C" void kernel_launch(void* const* d_in, const int* in_sizes, int n_in,
                              void* d_out, int out_size, void* d_ws, size_t ws_size,
                              hipStream_t stream) {
  const float* x        = (const float*)d_in[0];
  const float* w_off    = (const float*)d_in[1];
  const float* b_off    = (const float*)d_in[2];
  const float* w_main   = (const float*)d_in[3];
  const float* bn_gamma = (const float*)d_in[4];
  const float* bn_beta  = (const float*)d_in[5];
  const float* bn_mean  = (const float*)d_in[6];
  const float* bn_var   = (const float*)d_in[7];
  ushort* ws_u = (ushort*)d_ws;
  float*  ws_f = (float*)d_ws;
  float*  out  = (float*)d_out;

  int prep_tasks = C1 * NPT * C2 + 128 * 2 * 81 + C2;   // 315904
  prep<<<(prep_tasks + 255) / 256, 256, 0, stream>>>(
      w_main, w_off, bn_gamma, bn_beta, bn_mean, bn_var, ws_u, ws_f);
  transpose_x<<<BB * 4 * HH * 2, 256, 0, stream>>>(x, ws_u);
  off_conv_f32<<<BB * HH, 256, 0, stream>>>(x, b_off, ws_f);
  akconv_main_mfma8<<<BB * HH * 2, 512, 0, stream>>>(ws_u, ws_f, out);
}

// Round 7
// 179.568 us; speedup vs baseline: 6.9621x; 1.4036x over previous
//
#include <hip/hip_runtime.h>
#include <math.h>

typedef __attribute__((ext_vector_type(8))) short short8;
typedef __attribute__((ext_vector_type(4))) float f32x4;
typedef __attribute__((ext_vector_type(4))) int   int4v;

#define BB  4
#define C1  128
#define C2  256
#define HH  128
#define WW  128
#define NPT 9
#define HWN (HH*WW)

// ---- workspace byte offsets (all 256-aligned) ----
#define XT_OFF    0ull                        // bf16 xT[b][h][w][c]   : 16,777,216 B
#define WB2_OFF   16777216ull                 // bf16 wB2[n][o][c]     :    589,824 B
#define WOF32_OFF (WB2_OFF + 589824ull)       // f32  wof32[c][q][81]  :     82,944 B
#define BN_OFF    (WOF32_OFF + 82944ull)      // f32  bnA/bnB[256]     :      2,048 B
#define OFFP_OFF  (BN_OFF + 2048ull)          // f32  offp[pos][20]    :  5,242,880 B

__device__ __forceinline__ ushort f2bf(float f) {
  uint u = __builtin_bit_cast(uint, f);
  u += 0x7FFFu + ((u >> 16) & 1u);            // RNE
  return (ushort)(u >> 16);
}
__device__ __forceinline__ float bf2f(ushort u) {
  return __builtin_bit_cast(float, ((uint)u) << 16);
}

// ---------------- weight / BN prep ----------------
__global__ __launch_bounds__(256) void prep(
    const float* __restrict__ w_main, const float* __restrict__ w_off,
    const float* __restrict__ g, const float* __restrict__ be,
    const float* __restrict__ mu, const float* __restrict__ var,
    ushort* ws_u, float* ws_f) {
  int t = blockIdx.x * 256 + threadIdx.x;
  if (t < C1 * NPT * C2) {                        // wB2[n][o][c] = w_main[o][c][n]
    int c = t & 127, o = (t >> 7) & 255, n = t >> 15;
    ws_u[WB2_OFF / 2 + t] = f2bf(w_main[(o * C1 + c) * NPT + n]);
  } else if (t < C1 * NPT * C2 + 128 * 2 * 81) {  // wof32[(c*2+q)*81 + tap*9 + i]
    int e = t - C1 * NPT * C2;
    int c2 = e / 81, r81 = e - c2 * 81;
    int q = c2 & 1, c = c2 >> 1;
    int tap = r81 / 9, i = r81 - tap * 9;
    int oc = q * 9 + i;
    ws_f[WOF32_OFF / 4 + e] = w_off[(oc * C1 + c) * 9 + tap];
  } else if (t < C1 * NPT * C2 + 128 * 2 * 81 + C2) {
    int o = t - (C1 * NPT * C2 + 128 * 2 * 81);
    float inv = g[o] * rsqrtf(var[o] + 1e-5f);
    ws_f[BN_OFF / 4 + o] = inv;
    ws_f[BN_OFF / 4 + 256 + o] = be[o] - mu[o] * inv;
  }
}

// ---------------- x -> xT[b][h][w][c] bf16 (c-contiguous) ----------------
__global__ __launch_bounds__(256) void transpose_x(
    const float* __restrict__ x, ushort* ws_u) {
  __shared__ __align__(16) ushort tile[32][68];
  int bid = blockIdx.x;
  int wt = bid & 1, h = (bid >> 1) & 127, cb = (bid >> 8) & 3, b = bid >> 10;
  int c0 = cb * 32, w0 = wt * 64;
  int tid = threadIdx.x;
  int wl = tid & 63, rr = tid >> 6;
#pragma unroll
  for (int it = 0; it < 8; ++it) {
    int ci = it * 4 + rr;
    tile[ci][wl] = f2bf(x[(((size_t)b * C1 + c0 + ci) * HWN) + h * WW + w0 + wl]);
  }
  __syncthreads();
  int wl2 = tid >> 2, cg = tid & 3;
  short8 pk;
#pragma unroll
  for (int k = 0; k < 8; ++k) pk[k] = (short)tile[cg * 8 + k][wl2];
  *(short8*)(ws_u + XT_OFF / 2 +
             (((size_t)(b * HH + h) * WW + w0 + wl2) * C1 + c0 + cg * 8)) = pk;
}

// ---------------- fp32 offset conv, channel-split x4, no LDS, no barriers ----------------
// partial[cg][pos][20] lives in d_out scratch (overwritten later by the main kernel)
__global__ __launch_bounds__(256) void off_conv_part(
    const float* __restrict__ x, const float* __restrict__ b_off,
    const float* __restrict__ ws_f, float* __restrict__ part) {
  int blk = blockIdx.x;
  int cg = blk & 3, bh = blk >> 2;          // cg: channel group (32 ch)
  int h = bh & 127, b = bh >> 7;
  int tid = threadIdx.x;
  int w = tid & 127, q = tid >> 7;
  int qu = __builtin_amdgcn_readfirstlane(q);
  const float* wq = ws_f + WOF32_OFF / 4 + qu * 81;
  const float* xb = x + ((size_t)b * C1 + cg * 32) * HWN;

  float acc[9];
#pragma unroll
  for (int i = 0; i < 9; ++i) acc[i] = (cg == 0) ? b_off[qu * 9 + i] : 0.f;

  // clamped tap offsets + validity masks (no branches in the hot loop)
  int hc0 = (h >= 1) ? h - 1 : 0, hc2 = (h < 127) ? h + 1 : 127;
  int wc0 = (w >= 1) ? w - 1 : 0, wc2 = (w < 127) ? w + 1 : 127;
  bool vh0 = (h >= 1), vh2 = (h < 127);
  bool vw0 = (w >= 1), vw2 = (w < 127);
  int o[9];
  o[0] = hc0 * 128 + wc0; o[1] = hc0 * 128 + w; o[2] = hc0 * 128 + wc2;
  o[3] = h   * 128 + wc0; o[4] = h   * 128 + w; o[5] = h   * 128 + wc2;
  o[6] = hc2 * 128 + wc0; o[7] = hc2 * 128 + w; o[8] = hc2 * 128 + wc2;
  bool vm[9];
  vm[0] = vh0 && vw0; vm[1] = vh0; vm[2] = vh0 && vw2;
  vm[3] = vw0;        vm[4] = true; vm[5] = vw2;
  vm[6] = vh2 && vw0; vm[7] = vh2; vm[8] = vh2 && vw2;

  for (int ci = 0; ci < 32; ++ci) {
    const float* xc = xb + (size_t)ci * HWN;
    float xv[9];
#pragma unroll
    for (int k = 0; k < 9; ++k) {
      float r = xc[o[k]];               // always in-bounds (clamped)
      xv[k] = vm[k] ? r : 0.f;          // cndmask, no branch
    }
    const float* wp = wq + (cg * 32 + ci) * 162;   // wave-uniform -> s_load
#pragma unroll
    for (int tap = 0; tap < 9; ++tap)
#pragma unroll
      for (int i = 0; i < 9; ++i)
        acc[i] = fmaf(xv[tap], wp[tap * 9 + i], acc[i]);
  }
  int pos = (b * HH + h) * WW + w;
  float* pd = part + ((size_t)cg * 65536 + pos) * 20 + qu * 9;
#pragma unroll
  for (int i = 0; i < 9; ++i) pd[i] = acc[i];
}

// ---------------- reduce 4 partials -> offp (fixed-order fp32, deterministic) ----------------
__global__ __launch_bounds__(256) void off_reduce(
    const float* __restrict__ part, float* __restrict__ ws_f) {
  int e = blockIdx.x * 256 + threadIdx.x;   // over 65536*18
  if (e >= 65536 * 18) return;
  int pos = e / 18, oc = e - pos * 18;
  size_t i0 = (size_t)pos * 20 + oc;
  float s = part[i0]
          + part[i0 + (size_t)65536 * 20]
          + part[i0 + (size_t)2 * 65536 * 20]
          + part[i0 + (size_t)3 * 65536 * 20];
  ws_f[OFFP_OFF / 4 + i0] = s;
}

// ---------------- fused gather + MFMA GEMM + BN + SiLU (8-wave) ----------------
__global__ __launch_bounds__(512) void akconv_main_mfma8(
    const ushort* ws_u, const float* ws_f, float* out) {
  __shared__ __align__(16) int4v sidx[576];
  __shared__ __align__(16) f32x4 swgt[576];
  __shared__ __align__(16) ushort alds[2][8192];   // [buf][64 pos][128 c], oct^=(pos&7)

  int tid = threadIdx.x;
  int blk = blockIdx.x;
  // XCD-aware decode: each XCD (blk&7) owns one b-plane and one 64-row h-band
  int xcd = blk & 7, idx = blk >> 3;        // idx in 0..127
  int b  = xcd >> 1;
  int h  = ((xcd & 1) << 6) + (idx >> 1);
  int wt = idx & 1;
  int w0 = wt * 64;
  const float* offp = ws_f + OFFP_OFF / 4;

  // phase A: bilinear indices (byte offsets into xT b-plane) + weights
  for (int t = tid; t < 576; t += 512) {
    int n = t >> 6, wl = t & 63;
    int pos = (b * HH + h) * WW + w0 + wl;
    float ox = offp[pos * 20 + n];
    float oy = offp[pos * 20 + 9 + n];
    float px = ox + (float)(n / 3) + (float)h;
    float py = oy + (float)(n - (n / 3) * 3) + (float)(w0 + wl);
    px = fminf(fmaxf(px, 0.f), 127.f);
    py = fminf(fmaxf(py, 0.f), 127.f);
    float x0 = floorf(px), y0 = floorf(py);
    float x1 = fminf(x0 + 1.f, 127.f), y1 = fminf(y0 + 1.f, 127.f);
    f32x4 g;
    g[0] = (1.f + (x0 - px)) * (1.f + (y0 - py));
    g[1] = (1.f - (x1 - px)) * (1.f - (y1 - py));
    g[2] = (1.f + (x0 - px)) * (1.f - (y1 - py));
    g[3] = (1.f - (x1 - px)) * (1.f + (y0 - py));
    int ix0 = (int)x0, iy0 = (int)y0, ix1 = (int)x1, iy1 = (int)y1;
    int4v iv;
    iv[0] = (ix0 * WW + iy0) * 256;
    iv[1] = (ix1 * WW + iy1) * 256;
    iv[2] = (ix0 * WW + iy1) * 256;
    iv[3] = (ix1 * WW + iy0) * 256;
    sidx[t] = iv;
    swgt[t] = g;
  }

  const char* xTb = (const char*)ws_u + (size_t)b * (HWN * 256);
  const ushort* wB2 = ws_u + WB2_OFF / 2;
  int lane = tid & 63, r = lane & 15, kg = lane >> 4;
  int owu = __builtin_amdgcn_readfirstlane(tid >> 6) * 32;  // wave's 32-channel slice

  // per-thread build slots: two of (pos, 16B c-octet)
  int p0  = tid >> 4;                 // 0..31
  int p1  = p0 + 32;                  // 32..63
  int oct = tid & 15;
  int coff = oct * 16;                // byte offset within 256B c-row
  int wr0 = p0 * 128 + ((oct ^ (p0 & 7)) * 8);   // swizzled ushort index
  int wr1 = p1 * 128 + ((oct ^ (p1 & 7)) * 8);

  f32x4 acc[4][2];
#pragma unroll
  for (int mi = 0; mi < 4; ++mi)
#pragma unroll
    for (int oi = 0; oi < 2; ++oi) acc[mi][oi] = (f32x4)0.0f;

  __syncthreads();   // sidx/swgt visible

  short8 gv[2][4];
  f32x4 gw0, gw1;

#define GLOAD(nn)                                                       \
  {                                                                     \
    int4v iv0 = sidx[(nn) * 64 + p0];                                   \
    int4v iv1 = sidx[(nn) * 64 + p1];                                   \
    gw0 = swgt[(nn) * 64 + p0];                                         \
    gw1 = swgt[(nn) * 64 + p1];                                         \
    _Pragma("unroll")                                                   \
    for (int k = 0; k < 4; ++k) {                                       \
      gv[0][k] = *(const short8*)(xTb + iv0[k] + coff);                 \
      gv[1][k] = *(const short8*)(xTb + iv1[k] + coff);                 \
    }                                                                   \
  }

#define GCOMBINE(bufb)                                                  \
  {                                                                     \
    short8 pk0, pk1;                                                    \
    _Pragma("unroll")                                                   \
    for (int j = 0; j < 8; ++j) {                                       \
      float f0 = gw0[0] * bf2f((ushort)gv[0][0][j])                     \
               + gw0[1] * bf2f((ushort)gv[0][1][j])                     \
               + gw0[2] * bf2f((ushort)gv[0][2][j])                     \
               + gw0[3] * bf2f((ushort)gv[0][3][j]);                    \
      float f1 = gw1[0] * bf2f((ushort)gv[1][0][j])                     \
               + gw1[1] * bf2f((ushort)gv[1][1][j])                     \
               + gw1[2] * bf2f((ushort)gv[1][2][j])                     \
               + gw1[3] * bf2f((ushort)gv[1][3][j]);                    \
      pk0[j] = (short)f2bf(f0);                                         \
      pk1[j] = (short)f2bf(f1);                                         \
    }                                                                   \
    *(short8*)(&alds[bufb][wr0]) = pk0;                                 \
    *(short8*)(&alds[bufb][wr1]) = pk1;                                 \
  }

  // prologue: build n=0 into buf 0
  GLOAD(0);
  GCOMBINE(0);
  __syncthreads();

  for (int n = 0; n < 9; ++n) {
    int buf = n & 1;
    // 1) issue next-n gathers (latency hides under MFMA phase)
    if (n < 8) GLOAD(n + 1);
    // 2) MFMA over the current 128-channel slab
#pragma unroll
    for (int kc = 0; kc < 4; ++kc) {
      short8 b0 = *(const short8*)(wB2 + ((size_t)(n * C2 + owu + r) * C1 + kc * 32 + kg * 8));
      short8 b1 = *(const short8*)(wB2 + ((size_t)(n * C2 + owu + 16 + r) * C1 + kc * 32 + kg * 8));
#pragma unroll
      for (int mi = 0; mi < 4; ++mi) {
        short8 a = *(const short8*)(&alds[buf][(mi * 16 + r) * 128 + (((kc * 4 + kg) ^ (r & 7)) * 8)]);
        acc[mi][0] = __builtin_amdgcn_mfma_f32_16x16x32_bf16(b0, a, acc[mi][0], 0, 0, 0);
        acc[mi][1] = __builtin_amdgcn_mfma_f32_16x16x32_bf16(b1, a, acc[mi][1], 0, 0, 0);
      }
    }
    // 3) combine + write next slab
    if (n < 8) GCOMBINE(buf ^ 1);
    __syncthreads();
  }
#undef GLOAD
#undef GCOMBINE

  // epilogue: BN + SiLU, coalesced along w (col = position)
  const float* bnA = ws_f + BN_OFF / 4;
  const float* bnB = bnA + 256;
#pragma unroll
  for (int oi = 0; oi < 2; ++oi) {
#pragma unroll
    for (int mi = 0; mi < 4; ++mi) {
#pragma unroll
      for (int j = 0; j < 4; ++j) {
        int o = owu + oi * 16 + kg * 4 + j;
        float sA = bnA[o], sB = bnB[o];
        float v = acc[mi][oi][j] * sA + sB;
        float sv = v / (1.f + __expf(-v));
        out[(((size_t)b * C2 + o) * HWN) + h * WW + w0 + mi * 16 + r] = sv;
      }
    }
  }
}

extern "C" void kernel_launch(void* const* d_in, const int* in_sizes, int n_in,
                              void* d_out, int out_size, void* d_ws, size_t ws_size,
                              hipStream_t stream) {
  const float* x        = (const float*)d_in[0];
  const float* w_off    = (const float*)d_in[1];
  const float* b_off    = (const float*)d_in[2];
  const float* w_main   = (const float*)d_in[3];
  const float* bn_gamma = (const float*)d_in[4];
  const float* bn_beta  = (const float*)d_in[5];
  const float* bn_mean  = (const float*)d_in[6];
  const float* bn_var   = (const float*)d_in[7];
  ushort* ws_u = (ushort*)d_ws;
  float*  ws_f = (float*)d_ws;
  float*  out  = (float*)d_out;

  int prep_tasks = C1 * NPT * C2 + 128 * 2 * 81 + C2;   // 315904
  prep<<<(prep_tasks + 255) / 256, 256, 0, stream>>>(
      w_main, w_off, bn_gamma, bn_beta, bn_mean, bn_var, ws_u, ws_f);
  transpose_x<<<BB * 4 * HH * 2, 256, 0, stream>>>(x, ws_u);
  // offset conv: partials into d_out scratch (later fully overwritten by main)
  off_conv_part<<<4 * BB * HH, 256, 0, stream>>>(x, b_off, ws_f, out);
  off_reduce<<<(65536 * 18 + 255) / 256, 256, 0, stream>>>(out, ws_f);
  akconv_main_mfma8<<<BB * HH * 2, 512, 0, stream>>>(ws_u, ws_f, out);
}